// Round 1
// baseline (9109.925 us; speedup 1.0000x reference)
//
#include <hip/hip_runtime.h>

// LSTM: B=128, T=512, I=64, H=512, O=1, fp32 in/out.
// Persistent bf16-MFMA kernel: 256 WGs = 32 j-groups x 8 batch-groups.
// Each WG: 16 hidden units (64 gate rows) x 16 batch. Weights live in VGPRs
// as bf16 A-fragments; h double-buffered in d_ws (bf16 hi+lo split for
// near-fp32 recurrence precision); per-batch-group 32-WG spin barrier per step.

#define B_ 128
#define T_ 512
#define I_ 64
#define H_ 512

typedef __attribute__((ext_vector_type(8))) short short8;   // 8 bf16 (4 VGPRs)
typedef __attribute__((ext_vector_type(4))) float f32x4;    // 4 fp32 acc

__device__ inline unsigned f2bf_u(float f) {
  union { float f; unsigned u; } v; v.f = f;
  return (v.u + 0x7fffu + ((v.u >> 16) & 1u)) >> 16;  // RNE
}
__device__ inline float bf2f(unsigned s) {
  union { unsigned u; float f; } v; v.u = s << 16; return v.f;
}
__device__ inline float sigm(float x) { return 1.0f / (1.0f + __expf(-x)); }
// NaN-safe tanh via exp: +inf -> 1, 0 -> -1
__device__ inline float tanh_(float x) { return 1.0f - 2.0f / (1.0f + __expf(2.0f * x)); }

__global__ __launch_bounds__(256) void init_out(float* out, const float* b_ho) {
  int i = blockIdx.x * blockDim.x + threadIdx.x;
  if (i < B_ * T_) out[i] = b_ho[0];
}

__global__ __launch_bounds__(256) void lstm_kernel(
    const float* __restrict__ x,    // [B,T,I]
    const float* __restrict__ Wih,  // [4H,I]
    const float* __restrict__ Whh,  // [4H,H]
    const float* __restrict__ bih,  // [4H]
    const float* __restrict__ bhh,  // [4H]
    const float* __restrict__ Who,  // [1,H]
    float* __restrict__ out,        // [B,T]
    unsigned short* __restrict__ hbuf,  // 2 bufs x 2 parts x [B][H] bf16
    unsigned* __restrict__ cnts)        // 8 groups x 32-uint stride
{
  const int bid = blockIdx.x;
  const int jg = bid >> 3;      // 0..31  hidden-unit group (16 j each)
  const int bg = bid & 7;       // 0..7   batch group (16 b each)
  const int tid = threadIdx.x;
  const int w = tid >> 6;       // wave 0..3 (M-tile)
  const int l = tid & 63;
  const int l16 = l & 15;
  const int lk = l >> 4;        // 0..3

  // --- pointwise cell owned by this lane (D-frag: rows lk*4+r, col l16) ---
  const int jl = w * 4 + lk;            // 0..15 within WG
  const int j  = jg * 16 + jl;          // hidden index
  const int b  = bg * 16 + l16;         // batch index

  // --- A-fragment rows for this lane (A-frag: row l16 within wave tile) ---
  // WG row ordering: row = jl*4 + gate  (so D-regs = 4 gates of one cell)
  const int rowA  = w * 16 + l16;
  const int jlA   = rowA >> 2;
  const int gA    = rowA & 3;
  const int growA = gA * 512 + jg * 16 + jlA;   // global gate-row in [0,2048)

  // --- preload weights as bf16 A-frags (persistent in VGPRs) ---
  short8 a_hh[16], a_ih[2];
#pragma unroll
  for (int kt = 0; kt < 16; ++kt) {
    const float* p = Whh + growA * H_ + kt * 32 + lk * 8;
    short8 s;
#pragma unroll
    for (int e = 0; e < 8; ++e) s[e] = (short)f2bf_u(p[e]);
    a_hh[kt] = s;
  }
#pragma unroll
  for (int kt = 0; kt < 2; ++kt) {
    const float* p = Wih + growA * I_ + kt * 32 + lk * 8;
    short8 s;
#pragma unroll
    for (int e = 0; e < 8; ++e) s[e] = (short)f2bf_u(p[e]);
    a_ih[kt] = s;
  }

  float bias[4];
#pragma unroll
  for (int g = 0; g < 4; ++g) { int gr = g * 512 + j; bias[g] = bih[gr] + bhh[gr]; }
  const float whoj = Who[j];
  float c = 0.0f;

  __shared__ float red[4][16];

  unsigned short* const hb0 = hbuf;                   // buffer 0: [2][B][H]
  unsigned short* const hb1 = hbuf + 2 * B_ * H_;     // buffer 1
  unsigned* const cnt = cnts + bg * 32;               // 128B-spaced per group
  const float* const xrow = x + (size_t)b * (T_ * I_);

  for (int t = 0; t < T_; ++t) {
    const unsigned short* hp = (t & 1) ? hb1 : hb0;
    unsigned short* hn       = (t & 1) ? hb0 : hb1;

    f32x4 acc0 = {0.f, 0.f, 0.f, 0.f};
    f32x4 acc1 = {0.f, 0.f, 0.f, 0.f};

    // ---- x projection, hi+lo bf16 split (exact to ~2^-17) ----
#pragma unroll
    for (int kt = 0; kt < 2; ++kt) {
      const float4* p4 = (const float4*)(xrow + t * I_ + kt * 32 + lk * 8);
      float4 v0 = p4[0], v1 = p4[1];
      float v[8] = {v0.x, v0.y, v0.z, v0.w, v1.x, v1.y, v1.z, v1.w};
      short8 xhi, xlo;
#pragma unroll
      for (int e = 0; e < 8; ++e) {
        unsigned hh = f2bf_u(v[e]);
        xhi[e] = (short)hh;
        xlo[e] = (short)f2bf_u(v[e] - bf2f(hh));
      }
      acc0 = __builtin_amdgcn_mfma_f32_16x16x32_bf16(a_ih[kt], xhi, acc0, 0, 0, 0);
      acc1 = __builtin_amdgcn_mfma_f32_16x16x32_bf16(a_ih[kt], xlo, acc1, 0, 0, 0);
    }

    // ---- h recurrence, hi+lo split; two independent acc chains ----
    const int koff = lk * 8;
#pragma unroll
    for (int kt = 0; kt < 16; ++kt) {
      short8 bhi = *(const short8*)(hp + 0 * B_ * H_ + b * H_ + kt * 32 + koff);
      short8 blo = *(const short8*)(hp + 1 * B_ * H_ + b * H_ + kt * 32 + koff);
      acc0 = __builtin_amdgcn_mfma_f32_16x16x32_bf16(a_hh[kt], bhi, acc0, 0, 0, 0);
      acc1 = __builtin_amdgcn_mfma_f32_16x16x32_bf16(a_hh[kt], blo, acc1, 0, 0, 0);
    }

    // ---- pointwise (lane-local: 4 gates of one (j,b)) ----
    float gi = sigm(acc0.x + acc1.x + bias[0]);
    float gf = sigm(acc0.y + acc1.y + bias[1]);
    float gg = tanh_(acc0.z + acc1.z + bias[2]);
    float go = sigm(acc0.w + acc1.w + bias[3]);
    c = gf * c + gi * gg;
    float h = go * tanh_(c);

    // write h (hi + lo bf16) for next step
    unsigned hhi = f2bf_u(h);
    hn[0 * B_ * H_ + b * H_ + j] = (unsigned short)hhi;
    hn[1 * B_ * H_ + b * H_ + j] = (unsigned short)f2bf_u(h - bf2f(hhi));

    // ---- output projection partial: sum over this WG's 16 j ----
    float p = h * whoj;
    p += __shfl_xor(p, 16);
    p += __shfl_xor(p, 32);        // sum over 4 jl in wave; lanes<16 hold per-b
    if (l < 16) red[w][l] = p;
    __syncthreads();
    if (tid < 16) {
      float s = red[0][tid] + red[1][tid] + red[2][tid] + red[3][tid];
      atomicAdd(out + (size_t)(bg * 16 + tid) * T_ + t, s);
    }

    // ---- per-batch-group barrier (32 WGs share this h slice) ----
    __syncthreads();   // all lanes done reading hp / writing hn (+vmcnt drain)
    if (tid == 0) {
      __threadfence();  // device-scope release (cross-XCD L2 writeback)
      __hip_atomic_fetch_add(cnt, 1u, __ATOMIC_RELEASE, __HIP_MEMORY_SCOPE_AGENT);
      const unsigned target = 32u * (unsigned)(t + 1);
      while (__hip_atomic_load(cnt, __ATOMIC_ACQUIRE, __HIP_MEMORY_SCOPE_AGENT) < target) {
        __builtin_amdgcn_s_sleep(1);
      }
    }
    __syncthreads();
  }
}

extern "C" void kernel_launch(void* const* d_in, const int* in_sizes, int n_in,
                              void* d_out, int out_size, void* d_ws, size_t ws_size,
                              hipStream_t stream) {
  (void)in_sizes; (void)n_in; (void)out_size; (void)ws_size;
  const float* x   = (const float*)d_in[0];
  const float* Wih = (const float*)d_in[1];
  const float* Whh = (const float*)d_in[2];
  const float* bih = (const float*)d_in[3];
  const float* bhh = (const float*)d_in[4];
  const float* Who = (const float*)d_in[5];
  const float* bho = (const float*)d_in[6];
  float* out = (float*)d_out;

  unsigned short* hbuf = (unsigned short*)d_ws;
  const size_t hbytes = (size_t)2 * 2 * B_ * H_ * sizeof(unsigned short);  // 512 KiB
  unsigned* cnts = (unsigned*)((char*)d_ws + hbytes);

  hipMemsetAsync(d_ws, 0, hbytes + 8 * 32 * sizeof(unsigned), stream);
  init_out<<<(B_ * T_ + 255) / 256, 256, 0, stream>>>(out, bho);
  lstm_kernel<<<dim3(256), dim3(256), 0, stream>>>(x, Wih, Whh, bih, bhh, Who,
                                                   out, hbuf, cnts);
}

// Round 2
// 5457.019 us; speedup vs baseline: 1.6694x; 1.6694x over previous
//
#include <hip/hip_runtime.h>

// LSTM: B=128, T=512, I=64, H=512, O=1, fp32 in/out.
// 64 persistent WGs = 8 j-groups x 8 batch-groups; each WG: 64 hidden units
// (256 gate rows) x 16 batch. Weights as bf16 A-frags in VGPRs (~288/lane).
// h exchanged via L3-coherent (agent-scope, relaxed) atomics — NO cache
// flush/invalidate ops anywhere in the hot loop. Per-batch-group barrier:
// one release fetch_add per WG + relaxed spin (8 participants).
// Output projection: per-WG partials -> ws, reduced by a second tiny kernel.

#define B_ 128
#define T_ 512
#define I_ 64
#define H_ 512

typedef __attribute__((ext_vector_type(8))) short short8;   // 8 bf16
typedef __attribute__((ext_vector_type(4))) float f32x4;

__device__ inline unsigned f2bf_u(float f) {
  union { float f; unsigned u; } v; v.f = f;
  return (v.u + 0x7fffu + ((v.u >> 16) & 1u)) >> 16;  // RNE
}
__device__ inline float bf2f(unsigned s) {
  union { unsigned u; float f; } v; v.u = s << 16; return v.f;
}
__device__ inline float sigm(float x) { return 1.0f / (1.0f + __expf(-x)); }
__device__ inline float tanh_(float x) { return 1.0f - 2.0f / (1.0f + __expf(2.0f * x)); }

__global__ __launch_bounds__(256, 1) void lstm_kernel(
    const float* __restrict__ x,    // [B,T,I]
    const float* __restrict__ Wih,  // [4H,I]
    const float* __restrict__ Whh,  // [4H,H]
    const float* __restrict__ bih,  // [4H]
    const float* __restrict__ bhh,  // [4H]
    const float* __restrict__ Who,  // [1,H]
    float* __restrict__ part,       // [8 jg][B][T] fp32 partial outputs
    unsigned short* __restrict__ hbuf,  // 2 bufs x (hi[B][H], lo[B][H]) bf16
    unsigned* __restrict__ cnts)        // 8 groups x 32-uint stride
{
  const int bid = blockIdx.x;
  const int jg = bid >> 3;      // 0..7  hidden-unit group (64 j each)
  const int bg = bid & 7;       // 0..7  batch group (16 b each)
  const int tid = threadIdx.x;
  const int w = tid >> 6;       // wave 0..3
  const int l = tid & 63;
  const int l16 = l & 15;
  const int lk = l >> 4;        // 0..3
  const int b = bg * 16 + l16;

  // ---- preload weights as bf16 A-frags: 4 M-tiles/wave, persistent in VGPRs ----
  short8 a_hh[4][16], a_ih[4][2];
  float bias[4][4], who[4];
  float c[4] = {0.f, 0.f, 0.f, 0.f};

#pragma unroll
  for (int m = 0; m < 4; ++m) {
    // A-frag row for this lane in M-tile m; WG row ordering: row = jl*4 + gate
    const int rowA = w * 64 + m * 16 + l16;
    const int grow = (rowA & 3) * 512 + jg * 64 + (rowA >> 2);  // global gate row
#pragma unroll
    for (int kt = 0; kt < 16; ++kt) {
      const float* p = Whh + (size_t)grow * H_ + kt * 32 + lk * 8;
      short8 s;
#pragma unroll
      for (int e = 0; e < 8; ++e) s[e] = (short)f2bf_u(p[e]);
      a_hh[m][kt] = s;
    }
#pragma unroll
    for (int kt = 0; kt < 2; ++kt) {
      const float* p = Wih + (size_t)grow * I_ + kt * 32 + lk * 8;
      short8 s;
#pragma unroll
      for (int e = 0; e < 8; ++e) s[e] = (short)f2bf_u(p[e]);
      a_ih[m][kt] = s;
    }
    // D-frag cell owned by this lane in M-tile m: j = jg*64 + w*16 + m*4 + lk
    const int jm = jg * 64 + w * 16 + m * 4 + lk;
#pragma unroll
    for (int g = 0; g < 4; ++g) bias[m][g] = bih[g * 512 + jm] + bhh[g * 512 + jm];
    who[m] = Who[jm];
  }

  __shared__ float red[2][4][16];

  unsigned short* const hb0 = hbuf;
  unsigned short* const hb1 = hbuf + 2 * B_ * H_;
  unsigned* const cnt = cnts + bg * 32;
  const float* const xrow = x + (size_t)b * (T_ * I_);

  for (int t = 0; t < T_; ++t) {
    const unsigned short* hp = (t & 1) ? hb1 : hb0;
    unsigned short* hn       = (t & 1) ? hb0 : hb1;

    f32x4 acc[4][2];
#pragma unroll
    for (int m = 0; m < 4; ++m) {
      acc[m][0] = (f32x4){0.f, 0.f, 0.f, 0.f};
      acc[m][1] = (f32x4){0.f, 0.f, 0.f, 0.f};
    }

    // ---- x projection (barrier-independent; runs while others finish t-1) ----
#pragma unroll
    for (int kt = 0; kt < 2; ++kt) {
      const float4* p4 = (const float4*)(xrow + t * I_ + kt * 32 + lk * 8);
      float4 v0 = p4[0], v1 = p4[1];
      float v[8] = {v0.x, v0.y, v0.z, v0.w, v1.x, v1.y, v1.z, v1.w};
      short8 xhi, xlo;
#pragma unroll
      for (int e = 0; e < 8; ++e) {
        unsigned hh = f2bf_u(v[e]);
        xhi[e] = (short)hh;
        xlo[e] = (short)f2bf_u(v[e] - bf2f(hh));
      }
#pragma unroll
      for (int m = 0; m < 4; ++m) {
        acc[m][0] = __builtin_amdgcn_mfma_f32_16x16x32_bf16(a_ih[m][kt], xhi, acc[m][0], 0, 0, 0);
        acc[m][1] = __builtin_amdgcn_mfma_f32_16x16x32_bf16(a_ih[m][kt], xlo, acc[m][1], 0, 0, 0);
      }
    }

    // ---- wait: all 8 WGs of this batch group finished step t-1 ----
    if (t > 0) {
      const unsigned target = 32u * (unsigned)t;   // 8 WGs x 4 (added by tid0)
      while (__hip_atomic_load(cnt, __ATOMIC_RELAXED, __HIP_MEMORY_SCOPE_AGENT) < target) {
        __builtin_amdgcn_s_sleep(1);
      }
    }
    __builtin_amdgcn_fence(__ATOMIC_ACQUIRE, "workgroup");  // compiler barrier (no cache ops)

    // ---- h recurrence: B-frags via L3-coherent relaxed atomic loads ----
#pragma unroll
    for (int kt = 0; kt < 16; ++kt) {
      const unsigned long long* phi =
          (const unsigned long long*)(hp + (size_t)b * H_ + kt * 32 + lk * 8);
      const unsigned long long* plo =
          (const unsigned long long*)(hp + (size_t)(B_ * H_) + (size_t)b * H_ + kt * 32 + lk * 8);
      union { unsigned long long q[2]; short8 s; } uhi, ulo;
      uhi.q[0] = __hip_atomic_load(phi + 0, __ATOMIC_RELAXED, __HIP_MEMORY_SCOPE_AGENT);
      uhi.q[1] = __hip_atomic_load(phi + 1, __ATOMIC_RELAXED, __HIP_MEMORY_SCOPE_AGENT);
      ulo.q[0] = __hip_atomic_load(plo + 0, __ATOMIC_RELAXED, __HIP_MEMORY_SCOPE_AGENT);
      ulo.q[1] = __hip_atomic_load(plo + 1, __ATOMIC_RELAXED, __HIP_MEMORY_SCOPE_AGENT);
#pragma unroll
      for (int m = 0; m < 4; ++m) {
        acc[m][0] = __builtin_amdgcn_mfma_f32_16x16x32_bf16(a_hh[m][kt], uhi.s, acc[m][0], 0, 0, 0);
        acc[m][1] = __builtin_amdgcn_mfma_f32_16x16x32_bf16(a_hh[m][kt], ulo.s, acc[m][1], 0, 0, 0);
      }
    }

    // ---- pointwise (lane-local: 4 cells, each with its 4 gates) ----
    float p = 0.f;
#pragma unroll
    for (int m = 0; m < 4; ++m) {
      float gi = sigm(acc[m][0].x + acc[m][1].x + bias[m][0]);
      float gf = sigm(acc[m][0].y + acc[m][1].y + bias[m][1]);
      float gg = tanh_(acc[m][0].z + acc[m][1].z + bias[m][2]);
      float go = sigm(acc[m][0].w + acc[m][1].w + bias[m][3]);
      c[m] = gf * c[m] + gi * gg;
      float hv = go * tanh_(c[m]);
      p += hv * who[m];

      const int jm = jg * 64 + w * 16 + m * 4 + lk;
      unsigned hh = f2bf_u(hv);
      __hip_atomic_store(hn + (size_t)b * H_ + jm, (unsigned short)hh,
                         __ATOMIC_RELAXED, __HIP_MEMORY_SCOPE_AGENT);
      __hip_atomic_store(hn + (size_t)(B_ * H_) + (size_t)b * H_ + jm,
                         (unsigned short)f2bf_u(hv - bf2f(hh)),
                         __ATOMIC_RELAXED, __HIP_MEMORY_SCOPE_AGENT);
    }

    // ---- output projection partial: sum over this WG's 64 j ----
    p += __shfl_xor(p, 16);
    p += __shfl_xor(p, 32);          // now all lanes hold wave-sum for col l16
    if (l < 16) red[t & 1][w][l16] = p;
    __syncthreads();                  // also drains vmcnt: h stores complete
    if (tid < 16) {
      float s = red[t & 1][0][tid] + red[t & 1][1][tid] +
                red[t & 1][2][tid] + red[t & 1][3][tid];
      part[((size_t)jg * B_ + (size_t)(bg * 16 + tid)) * T_ + t] = s;
    }
    if (tid == 0) {
      __hip_atomic_fetch_add(cnt, 4u, __ATOMIC_RELEASE, __HIP_MEMORY_SCOPE_AGENT);
    }
  }
}

__global__ __launch_bounds__(256) void reduce_out(const float* __restrict__ part,
                                                  const float* __restrict__ b_ho,
                                                  float* __restrict__ out) {
  int i = blockIdx.x * blockDim.x + threadIdx.x;  // over B*T
  if (i < B_ * T_) {
    float s = b_ho[0];
#pragma unroll
    for (int g = 0; g < 8; ++g) s += part[(size_t)g * B_ * T_ + i];
    out[i] = s;
  }
}

extern "C" void kernel_launch(void* const* d_in, const int* in_sizes, int n_in,
                              void* d_out, int out_size, void* d_ws, size_t ws_size,
                              hipStream_t stream) {
  (void)in_sizes; (void)n_in; (void)out_size; (void)ws_size;
  const float* x   = (const float*)d_in[0];
  const float* Wih = (const float*)d_in[1];
  const float* Whh = (const float*)d_in[2];
  const float* bih = (const float*)d_in[3];
  const float* bhh = (const float*)d_in[4];
  const float* Who = (const float*)d_in[5];
  const float* bho = (const float*)d_in[6];
  float* out = (float*)d_out;

  // ws layout: hbuf (512 KiB) | part (2 MiB) | cnts (1 KiB)
  unsigned short* hbuf = (unsigned short*)d_ws;
  const size_t hbytes = (size_t)2 * 2 * B_ * H_ * sizeof(unsigned short);
  float* part = (float*)((char*)d_ws + hbytes);
  const size_t pbytes = (size_t)8 * B_ * T_ * sizeof(float);
  unsigned* cnts = (unsigned*)((char*)d_ws + hbytes + pbytes);

  hipMemsetAsync(d_ws, 0, hbytes, stream);                       // zero h state
  hipMemsetAsync((char*)d_ws + hbytes + pbytes, 0, 8 * 32 * sizeof(unsigned), stream);

  lstm_kernel<<<dim3(64), dim3(256), 0, stream>>>(x, Wih, Whh, bih, bhh, Who,
                                                  part, hbuf, cnts);
  reduce_out<<<(B_ * T_ + 255) / 256, 256, 0, stream>>>(part, bho, out);
}

// Round 3
// 4967.613 us; speedup vs baseline: 1.8339x; 1.0985x over previous
//
#include <hip/hip_runtime.h>

// LSTM: B=128, T=512, I=64, H=512, O=1, fp32 in/out.
// 64 persistent WGs = 8 j-groups x 8 batch-groups; each WG: 64 hidden units
// (256 gate rows) x 16 batch. Weights as bf16 A-frags resident in VGPR/AGPR.
// Cross-WG h exchange: sc1 (L3-coherent) relaxed stores/loads ONLY — no
// release/acquire cache-maintenance (no buffer_wbl2/buffer_inv) in the loop.
// Per-producer flags, wave-parallel polling. h stores coalesced via LDS
// transpose (16B/lane). Output projection partials -> ws, reduced after.

#define B_ 128
#define T_ 512
#define I_ 64
#define H_ 512

typedef __attribute__((ext_vector_type(8))) short short8;   // 8 bf16
typedef __attribute__((ext_vector_type(4))) float f32x4;

__device__ inline unsigned f2bf_u(float f) {
  union { float f; unsigned u; } v; v.f = f;
  return (v.u + 0x7fffu + ((v.u >> 16) & 1u)) >> 16;  // RNE
}
__device__ inline float bf2f(unsigned s) {
  union { unsigned u; float f; } v; v.u = s << 16; return v.f;
}
__device__ inline float sigm(float x) { return 1.0f / (1.0f + __expf(-x)); }
__device__ inline float tanh_(float x) { return 1.0f - 2.0f / (1.0f + __expf(2.0f * x)); }

__global__ __launch_bounds__(256, 1) void lstm_kernel(
    const float* __restrict__ x,    // [B,T,I]
    const float* __restrict__ Wih,  // [4H,I]
    const float* __restrict__ Whh,  // [4H,H]
    const float* __restrict__ bih,  // [4H]
    const float* __restrict__ bhh,  // [4H]
    const float* __restrict__ Who,  // [1,H]
    float* __restrict__ part,       // [8 jg][B][T] fp32 partial outputs
    unsigned short* __restrict__ hbuf,  // 2 bufs x (hi[B][H], lo[B][H]) bf16
    unsigned* __restrict__ flags)       // 64 flags x 32-uint stride (1 per WG)
{
  const int bid = blockIdx.x;
  const int jg = bid >> 3;      // 0..7  hidden-unit group (64 j each)
  const int bg = bid & 7;       // 0..7  batch group (16 b each)
  const int tid = threadIdx.x;
  const int w = tid >> 6;       // wave 0..3
  const int l = tid & 63;
  const int l16 = l & 15;
  const int lk = l >> 4;        // 0..3
  const int b = bg * 16 + l16;

  // ---- preload weights as bf16 A-frags: 4 M-tiles/wave, resident ----
  short8 a_hh[4][16], a_ih[4][2];
  float bias[4][4], who[4];
  float c[4] = {0.f, 0.f, 0.f, 0.f};

#pragma unroll
  for (int m = 0; m < 4; ++m) {
    const int rowA = w * 64 + m * 16 + l16;                    // WG row = jl*4+gate
    const int grow = (rowA & 3) * 512 + jg * 64 + (rowA >> 2); // global gate row
#pragma unroll
    for (int kt = 0; kt < 16; ++kt) {
      const float* p = Whh + (size_t)grow * H_ + kt * 32 + lk * 8;
      short8 s;
#pragma unroll
      for (int e = 0; e < 8; ++e) s[e] = (short)f2bf_u(p[e]);
      a_hh[m][kt] = s;
    }
#pragma unroll
    for (int kt = 0; kt < 2; ++kt) {
      const float* p = Wih + (size_t)grow * I_ + kt * 32 + lk * 8;
      short8 s;
#pragma unroll
      for (int e = 0; e < 8; ++e) s[e] = (short)f2bf_u(p[e]);
      a_ih[m][kt] = s;
    }
    const int jm = jg * 64 + w * 16 + m * 4 + lk;  // lane's cell in M-tile m
#pragma unroll
    for (int g = 0; g < 4; ++g) bias[m][g] = bih[g * 512 + jm] + bhh[g * 512 + jm];
    who[m] = Who[jm];
  }

  __shared__ unsigned short hlds[2][2][16][64];  // [parity][plane][b][j] 8 KiB
  __shared__ float red[2][4][16];

  unsigned short* const hb0 = hbuf;
  unsigned short* const hb1 = hbuf + 2 * B_ * H_;
  unsigned* const fbase = flags + (size_t)bg * 8 * 32;   // this bg's 8 flags
  unsigned* const myflag = fbase + (size_t)jg * 32;
  const float* const xrow = x + (size_t)b * (T_ * I_);

  for (int t = 0; t < T_; ++t) {
    const int pr = t & 1;
    const unsigned short* hp = pr ? hb1 : hb0;
    unsigned short* hn       = pr ? hb0 : hb1;

    f32x4 acc[4][2];
#pragma unroll
    for (int m = 0; m < 4; ++m) {
      acc[m][0] = (f32x4){0.f, 0.f, 0.f, 0.f};
      acc[m][1] = (f32x4){0.f, 0.f, 0.f, 0.f};
    }

    // ---- x projection (issues before the poll; overlaps neighbors' tail) ----
#pragma unroll
    for (int kt = 0; kt < 2; ++kt) {
      const float4* p4 = (const float4*)(xrow + t * I_ + kt * 32 + lk * 8);
      float4 v0 = p4[0], v1 = p4[1];
      float v[8] = {v0.x, v0.y, v0.z, v0.w, v1.x, v1.y, v1.z, v1.w};
      short8 xhi, xlo;
#pragma unroll
      for (int e = 0; e < 8; ++e) {
        unsigned hh = f2bf_u(v[e]);
        xhi[e] = (short)hh;
        xlo[e] = (short)f2bf_u(v[e] - bf2f(hh));
      }
#pragma unroll
      for (int m = 0; m < 4; ++m) {
        acc[m][0] = __builtin_amdgcn_mfma_f32_16x16x32_bf16(a_ih[m][kt], xhi, acc[m][0], 0, 0, 0);
        acc[m][1] = __builtin_amdgcn_mfma_f32_16x16x32_bf16(a_ih[m][kt], xlo, acc[m][1], 0, 0, 0);
      }
    }

    // ---- wave-parallel poll: all 8 producer flags of this bg >= t ----
    if (t > 0) {
      const unsigned* fp = fbase + (size_t)(l & 7) * 32;
      for (;;) {
        unsigned f = __hip_atomic_load(fp, __ATOMIC_RELAXED, __HIP_MEMORY_SCOPE_AGENT);
        if (__all(f >= (unsigned)t)) break;
        __builtin_amdgcn_s_sleep(1);
      }
    }
    __builtin_amdgcn_fence(__ATOMIC_ACQUIRE, "workgroup");  // compiler order only

    // ---- h recurrence: sc1 relaxed loads from L3, pipelined with MFMA ----
#pragma unroll
    for (int kt = 0; kt < 16; ++kt) {
      const unsigned long long* phi =
          (const unsigned long long*)(hp + (size_t)b * H_ + kt * 32 + lk * 8);
      const unsigned long long* plo =
          (const unsigned long long*)(hp + (size_t)(B_ * H_) + (size_t)b * H_ + kt * 32 + lk * 8);
      union { unsigned long long q[2]; short8 s; } uhi, ulo;
      uhi.q[0] = __hip_atomic_load(phi + 0, __ATOMIC_RELAXED, __HIP_MEMORY_SCOPE_AGENT);
      uhi.q[1] = __hip_atomic_load(phi + 1, __ATOMIC_RELAXED, __HIP_MEMORY_SCOPE_AGENT);
      ulo.q[0] = __hip_atomic_load(plo + 0, __ATOMIC_RELAXED, __HIP_MEMORY_SCOPE_AGENT);
      ulo.q[1] = __hip_atomic_load(plo + 1, __ATOMIC_RELAXED, __HIP_MEMORY_SCOPE_AGENT);
#pragma unroll
      for (int m = 0; m < 4; ++m) {
        acc[m][0] = __builtin_amdgcn_mfma_f32_16x16x32_bf16(a_hh[m][kt], uhi.s, acc[m][0], 0, 0, 0);
        acc[m][1] = __builtin_amdgcn_mfma_f32_16x16x32_bf16(a_hh[m][kt], ulo.s, acc[m][1], 0, 0, 0);
      }
    }

    // ---- pointwise + stage h into LDS (transpose for coalesced store) ----
    float p = 0.f;
#pragma unroll
    for (int m = 0; m < 4; ++m) {
      float gi = sigm(acc[m][0].x + acc[m][1].x + bias[m][0]);
      float gf = sigm(acc[m][0].y + acc[m][1].y + bias[m][1]);
      float gg = tanh_(acc[m][0].z + acc[m][1].z + bias[m][2]);
      float go = sigm(acc[m][0].w + acc[m][1].w + bias[m][3]);
      c[m] = gf * c[m] + gi * gg;
      float hv = go * tanh_(c[m]);
      p += hv * who[m];
      unsigned hh = f2bf_u(hv);
      const int jl = w * 16 + m * 4 + lk;
      hlds[pr][0][l16][jl] = (unsigned short)hh;
      hlds[pr][1][l16][jl] = (unsigned short)f2bf_u(hv - bf2f(hh));
    }

    // projection partial: sum over this WG's 64 j
    p += __shfl_xor(p, 16);
    p += __shfl_xor(p, 32);
    if (l < 16) red[pr][w][l16] = p;

    __syncthreads();  // (A) hlds + red visible

    // ---- coalesced h store: one contiguous 16B chunk per lane ----
    {
      const int flat = tid * 8;            // ushort index into hlds[pr] (2048)
      const int plane = flat >> 10;        // 0..1
      const int bb = (flat >> 6) & 15;     // b within group
      const int jj = flat & 63;            // j start (multiple of 8)
      const unsigned long long* src =
          (const unsigned long long*)&hlds[pr][plane][bb][jj];
      unsigned long long q0 = src[0], q1 = src[1];
      unsigned long long* dst = (unsigned long long*)
          (hn + (size_t)plane * (B_ * H_) + (size_t)(bg * 16 + bb) * H_ + jg * 64 + jj);
      __hip_atomic_store(dst + 0, q0, __ATOMIC_RELAXED, __HIP_MEMORY_SCOPE_AGENT);
      __hip_atomic_store(dst + 1, q1, __ATOMIC_RELAXED, __HIP_MEMORY_SCOPE_AGENT);
    }
    if (tid < 16) {
      float s = red[pr][0][tid] + red[pr][1][tid] + red[pr][2][tid] + red[pr][3][tid];
      part[((size_t)jg * B_ + (size_t)(bg * 16 + tid)) * T_ + t] = s;
    }

    __syncthreads();  // (B) per-wave vmcnt(0) drain: all h stores acked at L3

    if (tid == 0) {
      __hip_atomic_store(myflag, (unsigned)(t + 1),
                         __ATOMIC_RELAXED, __HIP_MEMORY_SCOPE_AGENT);
    }
  }
}

__global__ __launch_bounds__(256) void reduce_out(const float* __restrict__ part,
                                                  const float* __restrict__ b_ho,
                                                  float* __restrict__ out) {
  int i = blockIdx.x * blockDim.x + threadIdx.x;  // over B*T
  if (i < B_ * T_) {
    float s = b_ho[0];
#pragma unroll
    for (int g = 0; g < 8; ++g) s += part[(size_t)g * B_ * T_ + i];
    out[i] = s;
  }
}

extern "C" void kernel_launch(void* const* d_in, const int* in_sizes, int n_in,
                              void* d_out, int out_size, void* d_ws, size_t ws_size,
                              hipStream_t stream) {
  (void)in_sizes; (void)n_in; (void)out_size; (void)ws_size;
  const float* x   = (const float*)d_in[0];
  const float* Wih = (const float*)d_in[1];
  const float* Whh = (const float*)d_in[2];
  const float* bih = (const float*)d_in[3];
  const float* bhh = (const float*)d_in[4];
  const float* Who = (const float*)d_in[5];
  const float* bho = (const float*)d_in[6];
  float* out = (float*)d_out;

  // ws layout: hbuf (512 KiB) | part (2 MiB) | flags (8 KiB)
  unsigned short* hbuf = (unsigned short*)d_ws;
  const size_t hbytes = (size_t)2 * 2 * B_ * H_ * sizeof(unsigned short);
  float* part = (float*)((char*)d_ws + hbytes);
  const size_t pbytes = (size_t)8 * B_ * T_ * sizeof(float);
  unsigned* flags = (unsigned*)((char*)d_ws + hbytes + pbytes);

  hipMemsetAsync(d_ws, 0, hbytes, stream);  // zero h state
  hipMemsetAsync((char*)d_ws + hbytes + pbytes, 0, 64 * 32 * sizeof(unsigned), stream);

  lstm_kernel<<<dim3(64), dim3(256), 0, stream>>>(x, Wih, Whh, bih, bhh, Who,
                                                  part, hbuf, flags);
  reduce_out<<<(B_ * T_ + 255) / 256, 256, 0, stream>>>(part, bho, out);
}

// Round 4
// 3499.225 us; speedup vs baseline: 2.6034x; 1.4196x over previous
//
#include <hip/hip_runtime.h>

// LSTM: B=128, T=512, I=64, H=512, O=1, fp32 in/out.
// 64 persistent WGs = 8 jg x 8 bg; each WG: 64 hidden units x 16 batch.
// Weights resident as bf16 A-frags (VGPR/AGPR). Cross-WG h via sc0sc1
// (coherent, cache-bypass) loads/stores; per-producer flags; wave-parallel
// poll. R4: h loads issued as ONE batch of 32 inline-asm dwordx4 loads,
// consumed via counted vmcnt waits (removes 16 serialized L3 round trips);
// hlds padded [16][72] (bank-conflict-free transpose).

#define B_ 128
#define T_ 512
#define I_ 64
#define H_ 512

typedef __attribute__((ext_vector_type(8))) short short8;   // 8 bf16
typedef __attribute__((ext_vector_type(4))) float f32x4;
typedef __attribute__((ext_vector_type(4))) unsigned u32x4;

__device__ inline unsigned f2bf_u(float f) {
  union { float f; unsigned u; } v; v.f = f;
  return (v.u + 0x7fffu + ((v.u >> 16) & 1u)) >> 16;  // RNE
}
__device__ inline float bf2f(unsigned s) {
  union { unsigned u; float f; } v; v.u = s << 16; return v.f;
}
__device__ inline float sigm(float x) { return 1.0f / (1.0f + __expf(-x)); }
__device__ inline float tanh_(float x) { return 1.0f - 2.0f / (1.0f + __expf(2.0f * x)); }

// coherent 16B load, byte offset literal OFF, bypass L1/L2 (read at L3 point)
#define LOADQ(dst, base, OFF)                                               \
  asm volatile("global_load_dwordx4 %0, %1, off offset:" #OFF " sc0 sc1"    \
               : "=v"(dst) : "v"(base))

#define WAITV(N)                                    \
  asm volatile("s_waitcnt vmcnt(" #N ")" ::: "memory"); \
  __builtin_amdgcn_sched_barrier(0)

__global__ __launch_bounds__(256, 1) void lstm_kernel(
    const float* __restrict__ x,    // [B,T,I]
    const float* __restrict__ Wih,  // [4H,I]
    const float* __restrict__ Whh,  // [4H,H]
    const float* __restrict__ bih,  // [4H]
    const float* __restrict__ bhh,  // [4H]
    const float* __restrict__ Who,  // [1,H]
    float* __restrict__ part,       // [8 jg][B][T] fp32 partials
    unsigned short* __restrict__ hbuf,  // 2 bufs x (hi[B][H], lo[B][H]) bf16
    unsigned* __restrict__ flags)       // 64 flags x 32-uint stride
{
  const int bid = blockIdx.x;
  const int jg = bid >> 3;
  const int bg = bid & 7;
  const int tid = threadIdx.x;
  const int w = tid >> 6;
  const int l = tid & 63;
  const int l16 = l & 15;
  const int lk = l >> 4;
  const int b = bg * 16 + l16;

  // ---- resident weights: bf16 A-frags, 4 M-tiles/wave ----
  short8 a_hh[4][16], a_ih[4][2];
  float bias[4][4], who[4];
  float c[4] = {0.f, 0.f, 0.f, 0.f};

#pragma unroll
  for (int m = 0; m < 4; ++m) {
    const int rowA = w * 64 + m * 16 + l16;                    // WG row = jl*4+gate
    const int grow = (rowA & 3) * 512 + jg * 64 + (rowA >> 2); // global gate row
#pragma unroll
    for (int kt = 0; kt < 16; ++kt) {
      const float* p = Whh + (size_t)grow * H_ + kt * 32 + lk * 8;
      short8 s;
#pragma unroll
      for (int e = 0; e < 8; ++e) s[e] = (short)f2bf_u(p[e]);
      a_hh[m][kt] = s;
    }
#pragma unroll
    for (int kt = 0; kt < 2; ++kt) {
      const float* p = Wih + (size_t)grow * I_ + kt * 32 + lk * 8;
      short8 s;
#pragma unroll
      for (int e = 0; e < 8; ++e) s[e] = (short)f2bf_u(p[e]);
      a_ih[m][kt] = s;
    }
    const int jm = jg * 64 + w * 16 + m * 4 + lk;
#pragma unroll
    for (int g = 0; g < 4; ++g) bias[m][g] = bih[g * 512 + jm] + bhh[g * 512 + jm];
    who[m] = Who[jm];
  }

  __shared__ unsigned short hlds[2][2][16][72];  // padded: conflict-free transpose
  __shared__ float red[2][4][16];

  unsigned short* const hb0 = hbuf;
  unsigned short* const hb1 = hbuf + 2 * B_ * H_;
  unsigned* const fbase = flags + (size_t)bg * 8 * 32;
  unsigned* const myflag = fbase + (size_t)jg * 32;
  const float* const xrow = x + (size_t)b * (T_ * I_);

  for (int t = 0; t < T_; ++t) {
    const int pr = t & 1;
    const unsigned short* hp = pr ? hb1 : hb0;
    unsigned short* hn       = pr ? hb0 : hb1;

    f32x4 acc[4][2];
#pragma unroll
    for (int m = 0; m < 4; ++m) {
      acc[m][0] = (f32x4){0.f, 0.f, 0.f, 0.f};
      acc[m][1] = (f32x4){0.f, 0.f, 0.f, 0.f};
    }

    // ---- x projection (before the poll; overlaps neighbors' tail) ----
#pragma unroll
    for (int kt = 0; kt < 2; ++kt) {
      const float4* p4 = (const float4*)(xrow + t * I_ + kt * 32 + lk * 8);
      float4 v0 = p4[0], v1 = p4[1];
      float v[8] = {v0.x, v0.y, v0.z, v0.w, v1.x, v1.y, v1.z, v1.w};
      short8 xhi, xlo;
#pragma unroll
      for (int e = 0; e < 8; ++e) {
        unsigned hh = f2bf_u(v[e]);
        xhi[e] = (short)hh;
        xlo[e] = (short)f2bf_u(v[e] - bf2f(hh));
      }
#pragma unroll
      for (int m = 0; m < 4; ++m) {
        acc[m][0] = __builtin_amdgcn_mfma_f32_16x16x32_bf16(a_ih[m][kt], xhi, acc[m][0], 0, 0, 0);
        acc[m][1] = __builtin_amdgcn_mfma_f32_16x16x32_bf16(a_ih[m][kt], xlo, acc[m][1], 0, 0, 0);
      }
    }

    // ---- wave-parallel poll: all 8 producers of this bg finished t-1 ----
    if (t > 0) {
      const unsigned* fp = fbase + (size_t)(l & 7) * 32;
      for (;;) {
        unsigned f = __hip_atomic_load(fp, __ATOMIC_RELAXED, __HIP_MEMORY_SCOPE_AGENT);
        if (__all(f >= (unsigned)t)) break;
      }
    }
    __builtin_amdgcn_fence(__ATOMIC_ACQUIRE, "workgroup");

    // ---- h recurrence: batch-issue all 32 coherent 16B loads, then
    //      consume in 4 chunks gated by counted vmcnt ----
    u32x4 hh[16], hl[16];
    {
      const unsigned short* phi = hp + (size_t)b * H_ + lk * 8;
      const unsigned short* plo = phi + (size_t)(B_ * H_);
      LOADQ(hh[0],  phi, 0);    LOADQ(hl[0],  plo, 0);
      LOADQ(hh[1],  phi, 64);   LOADQ(hl[1],  plo, 64);
      LOADQ(hh[2],  phi, 128);  LOADQ(hl[2],  plo, 128);
      LOADQ(hh[3],  phi, 192);  LOADQ(hl[3],  plo, 192);
      LOADQ(hh[4],  phi, 256);  LOADQ(hl[4],  plo, 256);
      LOADQ(hh[5],  phi, 320);  LOADQ(hl[5],  plo, 320);
      LOADQ(hh[6],  phi, 384);  LOADQ(hl[6],  plo, 384);
      LOADQ(hh[7],  phi, 448);  LOADQ(hl[7],  plo, 448);
      LOADQ(hh[8],  phi, 512);  LOADQ(hl[8],  plo, 512);
      LOADQ(hh[9],  phi, 576);  LOADQ(hl[9],  plo, 576);
      LOADQ(hh[10], phi, 640);  LOADQ(hl[10], plo, 640);
      LOADQ(hh[11], phi, 704);  LOADQ(hl[11], plo, 704);
      LOADQ(hh[12], phi, 768);  LOADQ(hl[12], plo, 768);
      LOADQ(hh[13], phi, 832);  LOADQ(hl[13], plo, 832);
      LOADQ(hh[14], phi, 896);  LOADQ(hl[14], plo, 896);
      LOADQ(hh[15], phi, 960);  LOADQ(hl[15], plo, 960);
    }
#define MFMA_CHUNK(c)                                                         \
    _Pragma("unroll")                                                         \
    for (int k2 = 0; k2 < 4; ++k2) {                                          \
      const int kt = (c) * 4 + k2;                                            \
      union { u32x4 u; short8 s; } uh, ul;                                    \
      uh.u = hh[kt]; ul.u = hl[kt];                                           \
      _Pragma("unroll")                                                       \
      for (int m = 0; m < 4; ++m) {                                           \
        acc[m][0] = __builtin_amdgcn_mfma_f32_16x16x32_bf16(a_hh[m][kt], uh.s, acc[m][0], 0, 0, 0); \
        acc[m][1] = __builtin_amdgcn_mfma_f32_16x16x32_bf16(a_hh[m][kt], ul.s, acc[m][1], 0, 0, 0); \
      }                                                                       \
    }
    WAITV(24); MFMA_CHUNK(0)
    WAITV(16); MFMA_CHUNK(1)
    WAITV(8);  MFMA_CHUNK(2)
    WAITV(0);  MFMA_CHUNK(3)
#undef MFMA_CHUNK

    // ---- pointwise + stage h into padded LDS transpose ----
    float p = 0.f;
#pragma unroll
    for (int m = 0; m < 4; ++m) {
      float gi = sigm(acc[m][0].x + acc[m][1].x + bias[m][0]);
      float gf = sigm(acc[m][0].y + acc[m][1].y + bias[m][1]);
      float gg = tanh_(acc[m][0].z + acc[m][1].z + bias[m][2]);
      float go = sigm(acc[m][0].w + acc[m][1].w + bias[m][3]);
      c[m] = gf * c[m] + gi * gg;
      float hv = go * tanh_(c[m]);
      p += hv * who[m];
      unsigned hh2 = f2bf_u(hv);
      const int jl = w * 16 + m * 4 + lk;
      hlds[pr][0][l16][jl] = (unsigned short)hh2;
      hlds[pr][1][l16][jl] = (unsigned short)f2bf_u(hv - bf2f(hh2));
    }

    // projection partial over this WG's 64 j
    p += __shfl_xor(p, 16);
    p += __shfl_xor(p, 32);
    if (l < 16) red[pr][w][l16] = p;

    __syncthreads();  // (A) hlds + red visible

    // ---- coalesced h store: 16B per lane ----
    {
      const int plane = tid >> 7;          // 0..1
      const int idx = tid & 127;
      const int bb = idx >> 3;             // 0..15
      const int jj = (idx & 7) * 8;        // 0..56
      const unsigned long long* src =
          (const unsigned long long*)&hlds[pr][plane][bb][jj];
      unsigned long long q0 = src[0], q1 = src[1];
      unsigned long long* dst = (unsigned long long*)
          (hn + (size_t)plane * (B_ * H_) + (size_t)(bg * 16 + bb) * H_ + jg * 64 + jj);
      __hip_atomic_store(dst + 0, q0, __ATOMIC_RELAXED, __HIP_MEMORY_SCOPE_AGENT);
      __hip_atomic_store(dst + 1, q1, __ATOMIC_RELAXED, __HIP_MEMORY_SCOPE_AGENT);
    }
    if (tid < 16) {
      float s = red[pr][0][tid] + red[pr][1][tid] + red[pr][2][tid] + red[pr][3][tid];
      part[((size_t)jg * B_ + (size_t)(bg * 16 + tid)) * T_ + t] = s;
    }

    __syncthreads();  // (B) per-wave vmcnt drain: h stores acked at L3

    if (tid == 0) {
      __hip_atomic_store(myflag, (unsigned)(t + 1),
                         __ATOMIC_RELAXED, __HIP_MEMORY_SCOPE_AGENT);
    }
  }
}

__global__ __launch_bounds__(256) void reduce_out(const float* __restrict__ part,
                                                  const float* __restrict__ b_ho,
                                                  float* __restrict__ out) {
  int i = blockIdx.x * blockDim.x + threadIdx.x;
  if (i < B_ * T_) {
    float s = b_ho[0];
#pragma unroll
    for (int g = 0; g < 8; ++g) s += part[(size_t)g * B_ * T_ + i];
    out[i] = s;
  }
}

extern "C" void kernel_launch(void* const* d_in, const int* in_sizes, int n_in,
                              void* d_out, int out_size, void* d_ws, size_t ws_size,
                              hipStream_t stream) {
  (void)in_sizes; (void)n_in; (void)out_size; (void)ws_size;
  const float* x   = (const float*)d_in[0];
  const float* Wih = (const float*)d_in[1];
  const float* Whh = (const float*)d_in[2];
  const float* bih = (const float*)d_in[3];
  const float* bhh = (const float*)d_in[4];
  const float* Who = (const float*)d_in[5];
  const float* bho = (const float*)d_in[6];
  float* out = (float*)d_out;

  unsigned short* hbuf = (unsigned short*)d_ws;
  const size_t hbytes = (size_t)2 * 2 * B_ * H_ * sizeof(unsigned short);
  float* part = (float*)((char*)d_ws + hbytes);
  const size_t pbytes = (size_t)8 * B_ * T_ * sizeof(float);
  unsigned* flags = (unsigned*)((char*)d_ws + hbytes + pbytes);

  hipMemsetAsync(d_ws, 0, hbytes, stream);  // zero h state
  hipMemsetAsync((char*)d_ws + hbytes + pbytes, 0, 64 * 32 * sizeof(unsigned), stream);

  lstm_kernel<<<dim3(64), dim3(256), 0, stream>>>(x, Wih, Whh, bih, bhh, Who,
                                                  part, hbuf, flags);
  reduce_out<<<(B_ * T_ + 255) / 256, 256, 0, stream>>>(part, bho, out);
}